// Round 11
// baseline (5815.574 us; speedup 1.0000x reference)
//
#include <hip/hip_runtime.h>

// Problem constants (match reference)
#define TT 4096   // sequence length (torch "batch" acting as time)
#define SD 64     // shared features
#define PD 8      // per-device features
#define DD 32     // devices
#define HH 128    // hidden
#define NG 512    // 4*H gate rows
#define XD 72     // S+P
#define XPAIRS 36 // packed f16x2 pairs of x
#define WROW 37   // padded row stride (uints) for W_ih0 in LDS (fallback path)
#define GXTB 16   // t-tile of the gx precompute kernel
#define RING 64   // producer/consumer ring depth (steps)
#define RMASK 63

typedef _Float16 h2 __attribute__((ext_vector_type(2)));
typedef unsigned uv16 __attribute__((ext_vector_type(16)));
typedef unsigned uv4 __attribute__((ext_vector_type(4)));

// ---- X-macro machinery ----
#define LIST8(X) X(0) X(1) X(2) X(3) X(4) X(5) X(6) X(7)
#define LIST16(X) LIST8(X) \
  X(8) X(9) X(10) X(11) X(12) X(13) X(14) X(15)

#define LIST64(X) \
  X(0) X(1) X(2) X(3) X(4) X(5) X(6) X(7) \
  X(8) X(9) X(10) X(11) X(12) X(13) X(14) X(15) \
  X(16) X(17) X(18) X(19) X(20) X(21) X(22) X(23) \
  X(24) X(25) X(26) X(27) X(28) X(29) X(30) X(31) \
  X(32) X(33) X(34) X(35) X(36) X(37) X(38) X(39) \
  X(40) X(41) X(42) X(43) X(44) X(45) X(46) X(47) \
  X(48) X(49) X(50) X(51) X(52) X(53) X(54) X(55) \
  X(56) X(57) X(58) X(59) X(60) X(61) X(62) X(63)

#define QUADS16(X) \
  X(0,0,1,2,3)     X(1,4,5,6,7)     X(2,8,9,10,11)   X(3,12,13,14,15) \
  X(4,16,17,18,19) X(5,20,21,22,23) X(6,24,25,26,27) X(7,28,29,30,31) \
  X(8,32,33,34,35) X(9,36,37,38,39) X(10,40,41,42,43) X(11,44,45,46,47) \
  X(12,48,49,50,51) X(13,52,53,54,55) X(14,56,57,58,59) X(15,60,61,62,63)

// pack two floats into one uint of f16x2 (a = low element), RTE
__device__ __forceinline__ unsigned pack_h2(float a, float b) {
  unsigned short ua = __builtin_bit_cast(unsigned short, (_Float16)a);
  unsigned short ub = __builtin_bit_cast(unsigned short, (_Float16)b);
  return ((unsigned)ub << 16) | ua;
}
__device__ __forceinline__ unsigned short f16bits(float a) {
  return __builtin_bit_cast(unsigned short, (_Float16)a);
}
__device__ __forceinline__ float f16val(unsigned short u) {
  return (float)__builtin_bit_cast(_Float16, u);
}

// acc += dot(f16x2 w, f16x2 h), f32 accumulate.
// ROUND-11 CHANGE: NOT v_dot2_f32_f16. The cycle ledger across R3/R8/R9
// closes only if dot2 issues at ~8cy (quarter-rate VOP3P); the f32-FMA pipe
// is measured full-rate (2cy, m07). fpext(f16)*fpext(f16)+f32 folds to
// v_fma_mix_f32 (op_sel picks the f16 half; f32 accumulate; fp32 pipe) ->
// 2 mixes @2cy = 4cy per pair vs 8cy. Bit-identical to the old fallback
// semantics (exact f32 FMA per element), so absmax is unchanged.
__device__ __forceinline__ float dot2(unsigned w, unsigned h, float acc) {
  h2 wv = __builtin_bit_cast(h2, w), hv = __builtin_bit_cast(h2, h);
  float r = __builtin_fmaf((float)wv[0], (float)hv[0], acc);
  return __builtin_fmaf((float)wv[1], (float)hv[1], r);
}

__device__ __forceinline__ float fast_sigmoid(float x) {
  return 1.0f / (1.0f + __expf(-x));
}
__device__ __forceinline__ float fast_tanh(float x) {
  return 2.0f / (1.0f + __expf(-2.0f * x)) - 1.0f;
}

// DPP quad_perm cross-lane moves within 4-lane groups (pure VALU, no LDS):
// xor1 = quad_perm[1,0,3,2] = 0xB1 ; xor2 = quad_perm[2,3,0,1] = 0x4E
__device__ __forceinline__ float dppx1m(float x) {
  return __builtin_bit_cast(float,
      __builtin_amdgcn_update_dpp(0, __builtin_bit_cast(int, x), 0xB1, 0xF, 0xF, true));
}
__device__ __forceinline__ float dppx2m(float x) {
  return __builtin_bit_cast(float,
      __builtin_amdgcn_update_dpp(0, __builtin_bit_cast(int, x), 0x4E, 0xF, 0xF, true));
}
// sum across the 4-lane group (all lanes end with the group total)
__device__ __forceinline__ float bfly4(float x) {
  x += dppx1m(x);
  x += dppx2m(x);
  return x;
}

// LDS-only barrier: drains LDS ops (the h dbuf handoff) but NOT vmcnt, so
// ring stores / prefetch loads stay in flight across steps.
__device__ __forceinline__ void lds_barrier() {
  asm volatile("s_waitcnt lgkmcnt(0)" ::: "memory");
  __builtin_amdgcn_s_barrier();
  asm volatile("" ::: "memory");
}

// ---------------------------------------------------------------------------
// gx precompute: gx[d][t][u][gate] = f16( b0 + W_ih0_row . x[d][t] )
// TRANSPOSED inner layout (unit-major, gate-minor).
// ---------------------------------------------------------------------------
__global__ __launch_bounds__(512)
void gx_kernel(const float* __restrict__ shared_in,  // [T, S]
               const float* __restrict__ perdev,     // [D, T, P]
               const float* __restrict__ Wih0,       // [D, 4H, S+P]
               const float* __restrict__ b0,         // [D, 4H]
               unsigned short* __restrict__ gx)      // [D, T, 128, 4] f16
{
  const int d = blockIdx.y;
  const int t0 = blockIdx.x * GXTB;
  const int g = threadIdx.x;          // gate row 0..511
  const int u = g & 127;              // hidden unit
  const int gate = g >> 7;            // 0..3 (i,f,g,o)

  __shared__ unsigned xs[GXTB * XPAIRS];  // x tile, packed f16x2

  const float* p = Wih0 + (size_t)(d * NG + g) * XD;
  uv16 w0, w1;
  uv4 w2;
#pragma unroll
  for (int j = 0; j < 16; ++j) w0[j] = pack_h2(p[2 * j], p[2 * j + 1]);
#pragma unroll
  for (int j = 0; j < 16; ++j) w1[j] = pack_h2(p[32 + 2 * j], p[33 + 2 * j]);
#pragma unroll
  for (int j = 0; j < 4; ++j) w2[j] = pack_h2(p[64 + 2 * j], p[65 + 2 * j]);
  const float b0g = b0[d * NG + g];

  for (int i = g; i < GXTB * XPAIRS; i += 512) {
    int r = i / XPAIRS, j = i - r * XPAIRS, t = t0 + r;
    float a, b;
    if (j < SD / 2) {
      a = shared_in[t * SD + 2 * j];
      b = shared_in[t * SD + 2 * j + 1];
    } else {
      int k = 2 * (j - SD / 2);
      a = perdev[((size_t)d * TT + t) * PD + k];
      b = perdev[((size_t)d * TT + t) * PD + k + 1];
    }
    xs[i] = pack_h2(a, b);
  }
  __syncthreads();

#define WJ(j) ((j) < 16 ? w0[(j)] : ((j) < 32 ? w1[(j)-16] : w2[(j)-32]))
  for (int tt = 0; tt < GXTB; ++tt) {
    const unsigned* xr = &xs[tt * XPAIRS];
    float a0 = b0g, a1 = 0.f, a2 = 0.f, a3 = 0.f;
#pragma unroll
    for (int j = 0; j < XPAIRS; j += 4) {
      a0 = dot2(WJ(j + 0), xr[j + 0], a0);
      a1 = dot2(WJ(j + 1), xr[j + 1], a1);
      a2 = dot2(WJ(j + 2), xr[j + 2], a2);
      a3 = dot2(WJ(j + 3), xr[j + 3], a3);
    }
    gx[((size_t)d * TT + t0 + tt) * NG + u * 4 + gate] = f16bits((a0 + a1) + (a2 + a3));
  }
#undef WJ
}

// ---------------------------------------------------------------------------
// Round-11 = R9/R10 cross-CU layer pipeline with:
//  1. dot2 -> v_fma_mix_f32 (see dot2 comment — THE discriminating change).
//  2. SAME-XCD pairing: producer = block d (d<32), consumer = block d+32
//     -> both on XCD d%8 (round-robin dispatch heuristic) -> ring traffic
//     L2-local instead of cross-XCD through IC/HBM.
//  3. s_sleep(1) poll granularity (64cy instead of 512cy quantum).
// ---------------------------------------------------------------------------
__global__ __attribute__((amdgpu_flat_work_group_size(512, 512), amdgpu_waves_per_eu(2, 2)))
void lstm_split_kernel(const float* __restrict__ Whh0,        // [D, 4H, H]
                       const float* __restrict__ Wih1,        // [D, 4H, H]
                       const float* __restrict__ Whh1,        // [D, 4H, H]
                       const float* __restrict__ b1,          // [D, 4H]
                       const float* __restrict__ Wout,        // [D, H]
                       const float* __restrict__ bout,        // [D]
                       const unsigned short* __restrict__ gx, // [D, T, 128, 4] f16
                       float* __restrict__ out,               // [T, D]
                       unsigned short* __restrict__ h0buf,    // [D][RING][HH] f16
                       float* __restrict__ zbuf,              // [D][RING][NG] f32
                       int* __restrict__ prog,                // [D*16] producer progress
                       int* __restrict__ cprog)               // [D*16] consumer progress
{
  const int d = blockIdx.x & 31;           // device
  const bool producer = blockIdx.x < DD;   // blocks d and d+32 share XCD d%8
  const int tid = threadIdx.x;
  const int lam = tid & 3;
  const int u = tid >> 2;          // hidden unit 0..127
  const bool lp = (lam < 2);

  __shared__ __align__(16) unsigned hst_s[2][HH / 2]; // producer: h0 dbuf / consumer: h1 dbuf
  __shared__ float part2_s[16][HH];                   // consumer: wout*h1 ring (by t&15)
  __shared__ int flag_s;

  const float actS = (lam == 2) ? 2.f : 1.f;
  const float actA = (lam == 2) ? -1.f : 0.f;

  if (tid < HH / 2) { hst_s[0][tid] = 0u; hst_s[1][tid] = 0u; }

  if (producer) {
    // ---- weights: Whh0 wA..wD (16 each, K [lam*32,+32)); Wih1 K-lo wE..wH
    // (8 each, K [lam*16,+16)) ----
#define DWA(n) unsigned wA##n;
    LIST16(DWA)
#undef DWA
#define DWB(n) unsigned wB##n;
    LIST16(DWB)
#undef DWB
#define DWC(n) unsigned wC##n;
    LIST16(DWC)
#undef DWC
#define DWD(n) unsigned wD##n;
    LIST16(DWD)
#undef DWD
#define DWE(n) unsigned wE##n;
    LIST8(DWE)
#undef DWE
#define DWF(n) unsigned wF##n;
    LIST8(DWF)
#undef DWF
#define DWG(n) unsigned wG##n;
    LIST8(DWG)
#undef DWG
#define DWH(n) unsigned wH##n;
    LIST8(DWH)
#undef DWH
    {
      const float* pw = Whh0 + ((size_t)d * NG + u) * HH + lam * 32;
#define LWA(n) wA##n = pack_h2(pw[2 * (n)], pw[2 * (n) + 1]);
      LIST16(LWA)
#undef LWA
      pw += (size_t)128 * HH;
#define LWB(n) wB##n = pack_h2(pw[2 * (n)], pw[2 * (n) + 1]);
      LIST16(LWB)
#undef LWB
      pw += (size_t)128 * HH;
#define LWC(n) wC##n = pack_h2(pw[2 * (n)], pw[2 * (n) + 1]);
      LIST16(LWC)
#undef LWC
      pw += (size_t)128 * HH;
#define LWD(n) wD##n = pack_h2(pw[2 * (n)], pw[2 * (n) + 1]);
      LIST16(LWD)
#undef LWD
      const float* qw = Wih1 + ((size_t)d * NG + u) * HH + lam * 16;
#define LWE(n) wE##n = pack_h2(qw[2 * (n)], qw[2 * (n) + 1]);
      LIST8(LWE)
#undef LWE
      qw += (size_t)128 * HH;
#define LWF(n) wF##n = pack_h2(qw[2 * (n)], qw[2 * (n) + 1]);
      LIST8(LWF)
#undef LWF
      qw += (size_t)128 * HH;
#define LWG(n) wG##n = pack_h2(qw[2 * (n)], qw[2 * (n) + 1]);
      LIST8(LWG)
#undef LWG
      qw += (size_t)128 * HH;
#define LWH(n) wH##n = pack_h2(qw[2 * (n)], qw[2 * (n) + 1]);
      LIST8(LWH)
#undef LWH
    }

    const unsigned short* gp = gx + (size_t)d * TT * NG + tid;
    unsigned short gxc = gp[0], gxn = 0;
    unsigned short* h0base = h0buf + (size_t)d * RING * HH;
    float* zbase = zbuf + (size_t)d * RING * NG;
    float c0 = 0.f;
    int cons_seen = -1;

    __syncthreads();

    for (int k = 0; k <= TT; ++k) {
      const int rb = (k & 1) ^ 1;
      const int wb = k & 1;
      if (k + 1 < TT) gxn = gp[(size_t)(k + 1) * NG];

      const uint4* hp = (const uint4*)hst_s[rb];
      uint4 q0 = hp[lam * 4 + 0], q1 = hp[lam * 4 + 1],
            q2 = hp[lam * 4 + 2], q3 = hp[lam * 4 + 3];
      uint4 e0 = hp[lam * 2], e1 = hp[lam * 2 + 1];  // K-lo slice (broadcast)

      // ---- layer 0 for t=k ----
      if (k < TT) {
        float aA = 0.f, aB = 0.f, aC = 0.f, aD = 0.f;
#define A0S(j, HV) { aA = dot2(wA##j, HV, aA); aB = dot2(wB##j, HV, aB); \
                     aC = dot2(wC##j, HV, aC); aD = dot2(wD##j, HV, aD); }
        A0S(0, q0.x)  A0S(1, q0.y)  A0S(2, q0.z)  A0S(3, q0.w)
        A0S(4, q1.x)  A0S(5, q1.y)  A0S(6, q1.z)  A0S(7, q1.w)
        A0S(8, q2.x)  A0S(9, q2.y)  A0S(10, q2.z) A0S(11, q2.w)
        A0S(12, q3.x) A0S(13, q3.y) A0S(14, q3.z) A0S(15, q3.w)
#undef A0S
        aA = bfly4(aA); aB = bfly4(aB); aC = bfly4(aC); aD = bfly4(aD);
        float pre = (lam == 0) ? aA : (lam == 1) ? aB : (lam == 2) ? aC : aD;
        pre += f16val(gxc);
        float e = __expf(-actS * pre);
        float act = __builtin_fmaf(1.f / (1.f + e), actS, actA);
        float v1 = dppx1m(act);
        float lo = (lam & 1) ? v1 : act;
        float hi = (lam & 1) ? act : v1;
        float lo2 = dppx2m(lo);
        float hi2 = dppx2m(hi);
        float ig = lp ? lo : lo2;
        float fg = lp ? hi : hi2;
        float gg = lp ? lo2 : lo;
        float og = lp ? hi2 : hi;
        c0 = __builtin_fmaf(fg, c0, ig * gg);
        float h0n = og * fast_tanh(c0);
        if (lam == 0) {
          unsigned short hb = f16bits(h0n);
          ((unsigned short*)hst_s[wb])[u] = hb;
          h0base[(size_t)(k & RMASK) * HH + u] = hb;
        }
      }

      // ---- z_lo(k-1) = Wih1[:,0:64] . h0(k-1) ----
      if (k >= 1) {
        float aE = 0.f, aF = 0.f, aG = 0.f, aH = 0.f;
#define Z0S(j, HV) { aE = dot2(wE##j, HV, aE); aF = dot2(wF##j, HV, aF); \
                     aG = dot2(wG##j, HV, aG); aH = dot2(wH##j, HV, aH); }
        Z0S(0, e0.x) Z0S(1, e0.y) Z0S(2, e0.z) Z0S(3, e0.w)
        Z0S(4, e1.x) Z0S(5, e1.y) Z0S(6, e1.z) Z0S(7, e1.w)
#undef Z0S
        aE = bfly4(aE); aF = bfly4(aF); aG = bfly4(aG); aH = bfly4(aH);
        float zr = (lam == 0) ? aE : (lam == 1) ? aF : (lam == 2) ? aG : aH;
        zbase[(size_t)((k - 1) & RMASK) * NG + tid] = zr;
      }

      // ---- barrier: lgkm-only per step; FULL drain only at the publish ----
      if ((k & 7) == 7 || k == TT) {
        __syncthreads();   // vmcnt(0) drain of everyone's ring stores
        if (tid == 0) {
          __hip_atomic_store(&prog[d * 16], k, __ATOMIC_RELEASE, __HIP_MEMORY_SCOPE_AGENT);
          if (k < TT) {  // throttle: never more than 40 steps ahead (ring safety)
            int c = cons_seen;
            while (k - c > 40) {
              __builtin_amdgcn_s_sleep(1);
              c = __hip_atomic_load(&cprog[d * 16], __ATOMIC_ACQUIRE, __HIP_MEMORY_SCOPE_AGENT);
            }
            cons_seen = c;
          }
        }
        __syncthreads();
      } else {
        lds_barrier();
      }
      gxc = gxn;
    }
  } else {
    // ================= consumer =================
    // weights: Wih1 K-hi wE..wH (8 each, K [64+lam*16,+16)); Whh1 wI..wL
    // (16 each, K [lam*32,+32))
#define DWE(n) unsigned wE##n;
    LIST8(DWE)
#undef DWE
#define DWF(n) unsigned wF##n;
    LIST8(DWF)
#undef DWF
#define DWG(n) unsigned wG##n;
    LIST8(DWG)
#undef DWG
#define DWH(n) unsigned wH##n;
    LIST8(DWH)
#undef DWH
#define DWI(n) unsigned wI##n;
    LIST16(DWI)
#undef DWI
#define DWJ(n) unsigned wJ##n;
    LIST16(DWJ)
#undef DWJ
#define DWK(n) unsigned wK##n;
    LIST16(DWK)
#undef DWK
#define DWL(n) unsigned wL##n;
    LIST16(DWL)
#undef DWL
    {
      const float* qw = Wih1 + ((size_t)d * NG + u) * HH + 64 + lam * 16;
#define LWE(n) wE##n = pack_h2(qw[2 * (n)], qw[2 * (n) + 1]);
      LIST8(LWE)
#undef LWE
      qw += (size_t)128 * HH;
#define LWF(n) wF##n = pack_h2(qw[2 * (n)], qw[2 * (n) + 1]);
      LIST8(LWF)
#undef LWF
      qw += (size_t)128 * HH;
#define LWG(n) wG##n = pack_h2(qw[2 * (n)], qw[2 * (n) + 1]);
      LIST8(LWG)
#undef LWG
      qw += (size_t)128 * HH;
#define LWH(n) wH##n = pack_h2(qw[2 * (n)], qw[2 * (n) + 1]);
      LIST8(LWH)
#undef LWH
      const float* rw = Whh1 + ((size_t)d * NG + u) * HH + lam * 32;
#define LWI(n) wI##n = pack_h2(rw[2 * (n)], rw[2 * (n) + 1]);
      LIST16(LWI)
#undef LWI
      rw += (size_t)128 * HH;
#define LWJ(n) wJ##n = pack_h2(rw[2 * (n)], rw[2 * (n) + 1]);
      LIST16(LWJ)
#undef LWJ
      rw += (size_t)128 * HH;
#define LWK(n) wK##n = pack_h2(rw[2 * (n)], rw[2 * (n) + 1]);
      LIST16(LWK)
#undef LWK
      rw += (size_t)128 * HH;
#define LWL(n) wL##n = pack_h2(rw[2 * (n)], rw[2 * (n) + 1]);
      LIST16(LWL)
#undef LWL
    }
    const float b1sel = b1[(size_t)d * NG + u + lam * 128];
    const float woutu = Wout[(size_t)d * HH + u];
    const float boutd = bout[d];
    float c1 = 0.f;
    const unsigned short* h0base = h0buf + (size_t)d * RING * HH;
    const float* zbase = zbuf + (size_t)d * RING * NG;

    // initial poll: cover z(0..8) and h0(0..8)
    if (tid == 0) {
      int need = 9 > TT ? TT : 9;
      int p = -1;
      while (p < need) {
        __builtin_amdgcn_s_sleep(1);
        p = __hip_atomic_load(&prog[d * 16], __ATOMIC_ACQUIRE, __HIP_MEMORY_SCOPE_AGENT);
      }
      flag_s = p;
    }
    __syncthreads();

    // prologue loads: z(0), h0(0) K-hi slice
    float zc = zbase[tid];
    const uint4* h0r0 = (const uint4*)(h0base + 64);
    uint4 s0 = h0r0[lam * 2], s1 = h0r0[lam * 2 + 1];

    for (int t = 0; t <= TT; ++t) {
      if (t && (t & 7) == 0) {
        if (tid == 0) {
          int need = t + 9 > TT ? TT : t + 9;
          int p = flag_s;
          while (p < need) {
            __builtin_amdgcn_s_sleep(1);
            p = __hip_atomic_load(&prog[d * 16], __ATOMIC_ACQUIRE, __HIP_MEMORY_SCOPE_AGENT);
          }
          flag_s = p;
        }
        __syncthreads();
      }

      // ---- amortized output flush: every 8 steps all 8 waves in parallel,
      // wave w reduces t' = t-8+w (slots (t-8..t-1)&15, disjoint from this
      // step's write slot t&15).
      if (t >= 8 && (t & 7) == 0) {
        const int e = t - 8 + (tid >> 6);
        const int l = tid & 63;
        float pv = part2_s[e & 15][l] + part2_s[e & 15][l + 64];
#pragma unroll
        for (int off = 32; off > 0; off >>= 1) pv += __shfl_xor(pv, off, 64);
        if (l == 0) out[(size_t)e * DD + d] = pv + boutd;
      }

      // prefetch next-step z and h0 slice
      float zn = zc;
      uint4 n0 = s0, n1 = s1;
      if (t + 1 < TT) {
        zn = zbase[(size_t)((t + 1) & RMASK) * NG + tid];
        const uint4* hr = (const uint4*)(h0base + (size_t)((t + 1) & RMASK) * HH + 64);
        n0 = hr[lam * 2]; n1 = hr[lam * 2 + 1];
      }

      if (t < TT) {
        const int rb = (t & 1) ^ 1;
        const uint4* ip = (const uint4*)hst_s[rb];
        uint4 r0 = ip[lam * 4 + 0], r1 = ip[lam * 4 + 1],
              r2 = ip[lam * 4 + 2], r3 = ip[lam * 4 + 3];
        float aE = 0.f, aF = 0.f, aG = 0.f, aH = 0.f;
        float aI = 0.f, aJ = 0.f, aK = 0.f, aL = 0.f;
#define C1S(j, HV) { aE = dot2(wE##j, HV, aE); aF = dot2(wF##j, HV, aF); \
                     aG = dot2(wG##j, HV, aG); aH = dot2(wH##j, HV, aH); }
        C1S(0, s0.x) C1S(1, s0.y) C1S(2, s0.z) C1S(3, s0.w)
        C1S(4, s1.x) C1S(5, s1.y) C1S(6, s1.z) C1S(7, s1.w)
#undef C1S
#define C2S(j, HV) { aI = dot2(wI##j, HV, aI); aJ = dot2(wJ##j, HV, aJ); \
                     aK = dot2(wK##j, HV, aK); aL = dot2(wL##j, HV, aL); }
        C2S(0, r0.x)  C2S(1, r0.y)  C2S(2, r0.z)  C2S(3, r0.w)
        C2S(4, r1.x)  C2S(5, r1.y)  C2S(6, r1.z)  C2S(7, r1.w)
        C2S(8, r2.x)  C2S(9, r2.y)  C2S(10, r2.z) C2S(11, r2.w)
        C2S(12, r3.x) C2S(13, r3.y) C2S(14, r3.z) C2S(15, r3.w)
#undef C2S
        aE += aI; aF += aJ; aG += aK; aH += aL;
        aE = bfly4(aE); aF = bfly4(aF); aG = bfly4(aG); aH = bfly4(aH);
        float pre = (lam == 0) ? aE : (lam == 1) ? aF : (lam == 2) ? aG : aH;
        pre += zc + b1sel;
        float e = __expf(-actS * pre);
        float act = __builtin_fmaf(1.f / (1.f + e), actS, actA);
        float v1 = dppx1m(act);
        float lo = (lam & 1) ? v1 : act;
        float hi = (lam & 1) ? act : v1;
        float lo2 = dppx2m(lo);
        float hi2 = dppx2m(hi);
        float ig = lp ? lo : lo2;
        float fg = lp ? hi : hi2;
        float gg = lp ? lo2 : lo;
        float og = lp ? hi2 : hi;
        c1 = __builtin_fmaf(fg, c1, ig * gg);
        float h1n = og * fast_tanh(c1);
        if (lam == 0) {
          ((unsigned short*)hst_s[t & 1])[u] = f16bits(h1n);
          part2_s[t & 15][u] = woutu * h1n;
        }
      }

      lds_barrier();
      zc = zn; s0 = n0; s1 = n1;

      if ((t & 7) == 7) {
        if (tid == 0)
          __hip_atomic_store(&cprog[d * 16], t, __ATOMIC_RELEASE, __HIP_MEMORY_SCOPE_AGENT);
      }
    }
  }
}

// ---------------------------------------------------------------------------
// Mid-fallback (ws fits gx only): Round-3 single-block fused kernel.
// ---------------------------------------------------------------------------
__global__ __attribute__((amdgpu_flat_work_group_size(512, 512), amdgpu_waves_per_eu(2, 2)))
void lstm_fused_kernel(const float* __restrict__ Whh0, const float* __restrict__ Wih1,
                       const float* __restrict__ Whh1, const float* __restrict__ b1,
                       const float* __restrict__ Wout, const float* __restrict__ bout,
                       const unsigned short* __restrict__ gx, float* __restrict__ out)
{
  const int d = blockIdx.x;
  const int tid = threadIdx.x;
  const int lam = tid & 3;
  const int u = tid >> 2;
  const bool lp = (lam < 2);

  __shared__ __align__(16) unsigned h0_s[2][HH / 2];
  __shared__ __align__(16) unsigned h1_s[2][HH / 2];
  __shared__ float part2_s[2][HH];

#define DWA(n) unsigned wA##n;
  LIST16(DWA)
#undef DWA
#define DWB(n) unsigned wB##n;
  LIST16(DWB)
#undef DWB
#define DWC(n) unsigned wC##n;
  LIST16(DWC)
#undef DWC
#define DWD(n) unsigned wD##n;
  LIST16(DWD)
#undef DWD
#define DWE(n) unsigned wE##n;
  LIST16(DWE)
#undef DWE
#define DWF(n) unsigned wF##n;
  LIST16(DWF)
#undef DWF
#define DWG(n) unsigned wG##n;
  LIST16(DWG)
#undef DWG
#define DWH(n) unsigned wH##n;
  LIST16(DWH)
#undef DWH
#define DWI(n) unsigned wI##n;
  LIST16(DWI)
#undef DWI
#define DWJ(n) unsigned wJ##n;
  LIST16(DWJ)
#undef DWJ
#define DWK(n) unsigned wK##n;
  LIST16(DWK)
#undef DWK
#define DWL(n) unsigned wL##n;
  LIST16(DWL)
#undef DWL
  {
    const float* pw = Whh0 + ((size_t)d * NG + u) * HH + lam * 32;
#define LWA(n) wA##n = pack_h2(pw[2 * (n)], pw[2 * (n) + 1]);
    LIST16(LWA)
#undef LWA
    pw += (size_t)128 * HH;
#define LWB(n) wB##n = pack_h2(pw[2 * (n)], pw[2 * (n) + 1]);
    LIST16(LWB)
#undef LWB
    pw += (size_t)128 * HH;
#define LWC(n) wC##n = pack_h2(pw[2 * (n)], pw[2 * (n) + 1]);
    LIST16(LWC)
#undef LWC
    pw += (size_t)128 * HH;
#define LWD(n) wD##n = pack_h2(pw[2 * (n)], pw[2 * (n) + 1]);
    LIST16(LWD)
#undef LWD
    const float* qw = Wih1 + ((size_t)d * NG + u) * HH + lam * 32;
#define LWE(n) wE##n = pack_h2(qw[2 * (n)], qw[2 * (n) + 1]);
    LIST16(LWE)
#undef LWE
    qw += (size_t)128 * HH;
#define LWF(n) wF##n = pack_h2(qw[2 * (n)], qw[2 * (n) + 1]);
    LIST16(LWF)
#undef LWF
    qw += (size_t)128 * HH;
#define LWG(n) wG##n = pack_h2(qw[2 * (n)], qw[2 * (n) + 1]);
    LIST16(LWG)
#undef LWG
    qw += (size_t)128 * HH;
#define LWH(n) wH##n = pack_h2(qw[2 * (n)], qw[2 * (n) + 1]);
    LIST16(LWH)
#undef LWH
    const float* rw = Whh1 + ((size_t)d * NG + u) * HH + lam * 32;
#define LWI(n) wI##n = pack_h2(rw[2 * (n)], rw[2 * (n) + 1]);
    LIST16(LWI)
#undef LWI
    rw += (size_t)128 * HH;
#define LWJ(n) wJ##n = pack_h2(rw[2 * (n)], rw[2 * (n) + 1]);
    LIST16(LWJ)
#undef LWJ
    rw += (size_t)128 * HH;
#define LWK(n) wK##n = pack_h2(rw[2 * (n)], rw[2 * (n) + 1]);
    LIST16(LWK)
#undef LWK
    rw += (size_t)128 * HH;
#define LWL(n) wL##n = pack_h2(rw[2 * (n)], rw[2 * (n) + 1]);
    LIST16(LWL)
#undef LWL
  }

  const float actS = (lam == 2) ? 2.f : 1.f;
  const float actA = (lam == 2) ? -1.f : 0.f;
  const float b1sel = b1[(size_t)d * NG + u + lam * 128];
  const float woutu = Wout[(size_t)d * HH + u];
  const float boutd = bout[d];
  float c0 = 0.f, c1 = 0.f;

  if (tid < HH / 2) {
    h0_s[0][tid] = 0u; h0_s[1][tid] = 0u;
    h1_s[0][tid] = 0u; h1_s[1][tid] = 0u;
  }
  if (tid < HH) { part2_s[0][tid] = 0.f; part2_s[1][tid] = 0.f; }

  const unsigned short* gp = gx + (size_t)d * TT * NG + tid;
  unsigned short gxc = gp[0], gxn = 0;

  __syncthreads();

  for (int k = 0; k <= TT; ++k) {
    const int rb = (k & 1) ^ 1;
    const int wb = k & 1;
    if (k + 1 < TT) gxn = gp[(size_t)(k + 1) * NG];

    const uint4* hp = (const uint4*)h0_s[rb];
    const uint4* ip = (const uint4*)h1_s[rb];
    uint4 q0 = hp[lam * 4 + 0], q1 = hp[lam * 4 + 1],
          q2 = hp[lam * 4 + 2], q3 = hp[lam * 4 + 3];
    uint4 r0 = ip[lam * 4 + 0], r1 = ip[lam * 4 + 1],
          r2 = ip[lam * 4 + 2], r3 = ip[lam * 4 + 3];

    if (k >= 2 && tid < 64) {
      float pv = part2_s[rb][tid] + part2_s[rb][tid + 64];
#pragma unroll
      for (int off = 32; off > 0; off >>= 1) pv += __shfl_xor(pv, off, 64);
      if (tid == 0) out[(size_t)(k - 2) * DD + d] = pv + boutd;
    }

    if (k < TT) {
      float aA = 0.f, aB = 0.f, aC = 0.f, aD = 0.f;
#define A0S(j, HV) { aA = dot2(wA##j, HV, aA); aB = dot2(wB##j, HV, aB); \
                     aC = dot2(wC##j, HV, aC); aD = dot2(wD##j, HV, aD); }
      A0S(0, q0.x)  A0S(1, q0.y)  A0S(2, q0.z)  A0S(3, q0.w)
      A0S(4, q1.x)  A0S(5, q1.y)  A0S(6, q1.z)  A0S(7, q1.w)
      A0S(8, q2.x)  A0S(9, q2.y)  A0S(10, q2.z) A0S(11, q2.w)
      A0S(12, q3.x) A0S(13, q3.y) A0S(14, q3.z) A0S(15, q3.w)
#undef A0S
      aA = bfly4(aA); aB = bfly4(aB); aC = bfly4(aC); aD = bfly4(aD);
      float pre = (lam == 0) ? aA : (lam == 1) ? aB : (lam == 2) ? aC : aD;
      pre += f16val(gxc);
      float e = __expf(-actS * pre);
      float act = __builtin_fmaf(1.f / (1.f + e), actS, actA);
      float v1 = dppx1m(act);
      float lo = (lam & 1) ? v1 : act;
      float hi = (lam & 1) ? act : v1;
      float lo2 = dppx2m(lo);
      float hi2 = dppx2m(hi);
      float ig = lp ? lo : lo2;
      float fg = lp ? hi : hi2;
      float gg = lp ? lo2 : lo;
      float og = lp ? hi2 : hi;
      c0 = __builtin_fmaf(fg, c0, ig * gg);
      float h0n = og * fast_tanh(c0);
      if (lam == 0) ((unsigned short*)h0_s[wb])[u] = f16bits(h0n);
    }

    if (k >= 1) {
      float aE = 0.f, aF = 0.f, aG = 0.f, aH = 0.f;
#define E0S(j, HV) { aE = dot2(wE##j, HV, aE); aF = dot2(wF##j, HV, aF); \
                     aG = dot2(wG##j, HV, aG); aH = dot2(wH##j, HV, aH); }
      E0S(0, q0.x)  E0S(1, q0.y)  E0S(2, q0.z)  E0S(3, q0.w)
      E0S(4, q1.x)  E0S(5, q1.y)  E0S(6, q1.z)  E0S(7, q1.w)
      E0S(8, q2.x)  E0S(9, q2.y)  E0S(10, q2.z) E0S(11, q2.w)
      E0S(12, q3.x) E0S(13, q3.y) E0S(14, q3.z) E0S(15, q3.w)
#undef E0S
#define I0S(j, HV) { aE = dot2(wI##j, HV, aE); aF = dot2(wJ##j, HV, aF); \
                     aG = dot2(wK##j, HV, aG); aH = dot2(wL##j, HV, aH); }
      I0S(0, r0.x)  I0S(1, r0.y)  I0S(2, r0.z)  I0S(3, r0.w)
      I0S(4, r1.x)  I0S(5, r1.y)  I0S(6, r1.z)  I0S(7, r1.w)
      I0S(8, r2.x)  I0S(9, r2.y)  I0S(10, r2.z) I0S(11, r2.w)
      I0S(12, r3.x) I0S(13, r3.y) I0S(14, r3.z) I0S(15, r3.w)
#undef I0S
      aE = bfly4(aE); aF = bfly4(aF); aG = bfly4(aG); aH = bfly4(aH);
      float pre = (lam == 0) ? aE : (lam == 1) ? aF : (lam == 2) ? aG : aH;
      pre += b1sel;
      float e = __expf(-actS * pre);
      float act = __builtin_fmaf(1.f / (1.f + e), actS, actA);
      float v1 = dppx1m(act);
      float lo = (lam & 1) ? v1 : act;
      float hi = (lam & 1) ? act : v1;
      float lo2 = dppx2m(lo);
      float hi2 = dppx2m(hi);
      float ig = lp ? lo : lo2;
      float fg = lp ? hi : hi2;
      float gg = lp ? lo2 : lo;
      float og = lp ? hi2 : hi;
      c1 = __builtin_fmaf(fg, c1, ig * gg);
      float h1n = og * fast_tanh(c1);
      if (lam == 0) {
        ((unsigned short*)h1_s[wb])[u] = f16bits(h1n);
        part2_s[wb][u] = woutu * h1n;
      }
    }

    __syncthreads();
    gxc = gxn;
  }

  if (tid < 64) {
    float pv = part2_s[TT & 1][tid] + part2_s[TT & 1][tid + 64];
#pragma unroll
    for (int off = 32; off > 0; off >>= 1) pv += __shfl_xor(pv, off, 64);
    if (tid == 0) out[(size_t)(TT - 1) * DD + d] = pv + boutd;
  }
}

// ---------------------------------------------------------------------------
// Last fallback (no workspace): previous-session kernel, non-PRE path only.
// ---------------------------------------------------------------------------
template <bool PRE>
__global__ __attribute__((amdgpu_flat_work_group_size(512, 512), amdgpu_waves_per_eu(2, 2)))
void lstm_pd_kernel(const float* __restrict__ shared_in, const float* __restrict__ perdev,
                    const float* __restrict__ Wih0, const float* __restrict__ Whh0,
                    const float* __restrict__ b0, const float* __restrict__ Wih1,
                    const float* __restrict__ Whh1, const float* __restrict__ b1,
                    const float* __restrict__ Wout, const float* __restrict__ bout,
                    const unsigned short* __restrict__ gx, float* __restrict__ out)
{
  const int d = blockIdx.x;
  const int g = threadIdx.x;
  const int lane = g & 63;
  const int wave = g >> 6;

  __shared__ float act0_s[NG];
  __shared__ float act1_s[NG];
  __shared__ __align__(16) unsigned h0_s[HH / 2];
  __shared__ __align__(16) unsigned h1_s[HH / 2];
  __shared__ __align__(16) unsigned x_s[PRE ? 4 : (XPAIRS + 4)];
  __shared__ unsigned wih0_s[PRE ? 1 : (NG * WROW)];
  __shared__ float part_s[2];

#define DW(n) unsigned wa##n, wi##n, wh##n;
  LIST64(DW)
#undef DW
  {
    const float* pa = Whh0 + (size_t)(d * NG + g) * HH;
    const float* pi = Wih1 + (size_t)(d * NG + g) * HH;
    const float* ph = Whh1 + (size_t)(d * NG + g) * HH;
#define SW(n) wa##n = pack_h2(pa[2 * (n)], pa[2 * (n) + 1]); \
              wi##n = pack_h2(pi[2 * (n)], pi[2 * (n) + 1]); \
              wh##n = pack_h2(ph[2 * (n)], ph[2 * (n) + 1]);
    LIST64(SW)
#undef SW
  }

  float b0g = 0.f;
  if (!PRE) {
    const float* p = Wih0 + (size_t)(d * NG + g) * XD;
    for (int j = 0; j < XPAIRS; ++j) wih0_s[g * WROW + j] = pack_h2(p[2 * j], p[2 * j + 1]);
    b0g = b0[d * NG + g];
  }
  const float b1g = b1[d * NG + g];
  const bool is_tanh_gate = ((g >> 7) == 2);
  float c0 = 0.f, c1 = 0.f;
  const float woutu = (g < HH) ? Wout[d * HH + g] : 0.f;
  const float boutd = bout[d];

  if (g < HH / 2) { h0_s[g] = 0u; h1_s[g] = 0u; }

  float xa = 0.f, xb = 0.f;
  if (!PRE && g < XPAIRS) {
    if (g < SD / 2) {
      xa = shared_in[0 * SD + 2 * g];
      xb = shared_in[0 * SD + 2 * g + 1];
    } else {
      int k = 2 * (g - SD / 2);
      xa = perdev[((size_t)d * TT + 0) * PD + k];
      xb = perdev[((size_t)d * TT + 0) * PD + k + 1];
    }
  }

  __syncthreads();

  for (int t = 0; t < TT; ++t) {
    if (!PRE) {
      if (g < XPAIRS) x_s[g] = pack_h2(xa, xb);
      __syncthreads();
    }

    float a0 = b0g, a1 = 0.f, a2 = 0.f, a3 = 0.f;
    if (!PRE) {
      const unsigned* wrow = &wih0_s[g * WROW];
#pragma unroll
      for (int j = 0; j < XPAIRS; j += 4) {
        a0 = dot2(wrow[j + 0], x_s[j + 0], a0);
        a1 = dot2(wrow[j + 1], x_s[j + 1], a1);
        a2 = dot2(wrow[j + 2], x_s[j + 2], a2);
        a3 = dot2(wrow[j + 3], x_s[j + 3], a3);
      }
    }
    {
      const uint4* h4 = (const uint4*)h0_s;
#define DA(q, n0, n1, n2, n3) { \
      uint4 hv = h4[q]; \
      a0 = dot2(wa##n0, hv.x, a0); a1 = dot2(wa##n1, hv.y, a1); \
      a2 = dot2(wa##n2, hv.z, a2); a3 = dot2(wa##n3, hv.w, a3); }
      QUADS16(DA)
#undef DA
      float pre = (a0 + a1) + (a2 + a3);
      act0_s[g] = is_tanh_gate ? fast_tanh(pre) : fast_sigmoid(pre);
    }
    __syncthreads();

    if (g == 0 && t > 0) out[(size_t)(t - 1) * DD + d] = part_s[0] + part_s[1] + boutd;

    if (!PRE && g < XPAIRS && t + 1 < TT) {
      int tn = t + 1;
      if (g < SD / 2) {
        xa = shared_in[tn * SD + 2 * g];
        xb = shared_in[tn * SD + 2 * g + 1];
      } else {
        int k = 2 * (g - SD / 2);
        xa = perdev[((size_t)d * TT + tn) * PD + k];
        xb = perdev[((size_t)d * TT + tn) * PD + k + 1];
      }
    }

    if (g < HH) {
      float ig = act0_s[g], fg = act0_s[g + 128], gg = act0_s[g + 256], og = act0_s[g + 384];
      c0 = __builtin_fmaf(fg, c0, ig * gg);
      float h0n = og * fast_tanh(c0);
      ((unsigned short*)h0_s)[g] = f16bits(h0n);
    }
    __syncthreads();

    a0 = b1g; a1 = 0.f; a2 = 0.f; a3 = 0.f;
    {
      const uint4* h4 = (const uint4*)h0_s;
#define DI(q, n0, n1, n2, n3) { \
      uint4 hv = h4[q]; \
      a0 = dot2(wi##n0, hv.x, a0); a1 = dot2(wi##n1, hv.y, a1); \
      a2 = dot2(wi##n2, hv.z, a2); a3 = dot2(wi##n3, hv.w, a3); }
      QUADS16(DI)
#undef DI
      const uint4* g4 = (const uint4*)h1_s;
#define DH(q, n0, n1, n2, n3) { \
      uint4 hv = g4[q]; \
      a0 = dot2(wh##n0, hv.x, a0); a1 = dot2(wh##n1, hv.y, a1); \
      a2 = dot2(wh##n2, hv.z, a2); a3 = dot2(wh##n3, hv.w, a3); }
      QUADS16(DH)
#undef DH
      float pre = (a0 + a1) + (a2 + a3);
      act1_s[g] = is_tanh_gate ? fast_tanh(pre) : fast_sigmoid(pre);
    }
    __syncthreads();

    if (g < HH) {
      float ig = act1_s[g], fg = act1_s[g + 128], gg = act1_s[g + 256], og = act1_s[g + 384];
      c1 = __builtin_fmaf(fg, c1, ig * gg);
      float h1n = og * fast_tanh(c1);
      ((unsigned short*)h1_s)[g] = f16bits(h1n);
      float p = woutu * h1n;
#pragma unroll
      for (int off = 32; off > 0; off >>= 1) p += __shfl_down(p, off, 64);
      if (lane == 0) part_s[wave] = p;
    }
  }

  __syncthreads();
  if (g == 0) out[(size_t)(TT - 1) * DD + d] = part_s[0] + part_s[1] + boutd;
}

extern "C" void kernel_launch(void* const* d_in, const int* in_sizes, int n_in,
                              void* d_out, int out_size, void* d_ws, size_t ws_size,
                              hipStream_t stream) {
  const float* shared_in = (const float*)d_in[0];
  const float* perdev    = (const float*)d_in[1];
  const float* Wih0      = (const float*)d_in[2];
  const float* Whh0      = (const float*)d_in[3];
  const float* b0        = (const float*)d_in[4];
  const float* Wih1      = (const float*)d_in[5];
  const float* Whh1      = (const float*)d_in[6];
  const float* b1        = (const float*)d_in[7];
  const float* Wout      = (const float*)d_in[8];
  const float* bout      = (const float*)d_in[9];
  float* out = (float*)d_out;

  const size_t gx_bytes = (size_t)DD * TT * NG * sizeof(unsigned short);  // 128 MB
  // split-path workspace layout after gx:
  const size_t off_h0 = gx_bytes;                        // 512 KB used
  const size_t off_z  = gx_bytes + (1u << 20);           // 4 MB used
  const size_t off_fl = gx_bytes + (5u << 20);           // 16 KB used (prog+cprog)
  const size_t need_split = off_fl + 16384;

  if (ws_size >= need_split) {
    char* ws = (char*)d_ws;
    unsigned short* gxp = (unsigned short*)ws;
    unsigned short* h0buf = (unsigned short*)(ws + off_h0);
    float* zbuf = (float*)(ws + off_z);
    int* prog = (int*)(ws + off_fl);
    int* cprog = (int*)(ws + off_fl + 8192);
    hipMemsetAsync(ws + off_fl, 0xFF, 16384, stream);    // prog/cprog = -1
    gx_kernel<<<dim3(TT / GXTB, DD), dim3(512), 0, stream>>>(shared_in, perdev, Wih0, b0, gxp);
    lstm_split_kernel<<<dim3(2 * DD), dim3(512), 0, stream>>>(
        Whh0, Wih1, Whh1, b1, Wout, bout, gxp, out, h0buf, zbuf, prog, cprog);
  } else if (ws_size >= gx_bytes) {
    unsigned short* gxp = (unsigned short*)d_ws;
    gx_kernel<<<dim3(TT / GXTB, DD), dim3(512), 0, stream>>>(shared_in, perdev, Wih0, b0, gxp);
    lstm_fused_kernel<<<dim3(DD), dim3(512), 0, stream>>>(
        Whh0, Wih1, Whh1, b1, Wout, bout, gxp, out);
  } else {
    lstm_pd_kernel<false><<<dim3(DD), dim3(NG), 0, stream>>>(
        shared_in, perdev, Wih0, Whh0, b0, Wih1, Whh1, b1, Wout, bout, nullptr, out);
  }
}

// Round 12
// 4658.390 us; speedup vs baseline: 1.2484x; 1.2484x over previous
//
#include <hip/hip_runtime.h>

// Problem constants (match reference)
#define TT 4096   // sequence length (torch "batch" acting as time)
#define SD 64     // shared features
#define PD 8      // per-device features
#define DD 32     // devices
#define HH 128    // hidden
#define NG 512    // 4*H gate rows
#define XD 72     // S+P
#define XPAIRS 36 // packed f16x2 pairs of x
#define WROW 37   // padded row stride (uints) for W_ih0 in LDS (fallback path)
#define GXTB 16   // t-tile of the gx precompute kernel
#define RING 64   // producer/consumer ring depth (steps)
#define RMASK 63

typedef _Float16 h2 __attribute__((ext_vector_type(2)));
typedef unsigned uv16 __attribute__((ext_vector_type(16)));
typedef unsigned uv4 __attribute__((ext_vector_type(4)));

#if defined(__has_builtin)
#  if __has_builtin(__builtin_amdgcn_fdot2)
#    define USE_DOT2 1
#  endif
#endif

// ---- X-macro machinery ----
#define LIST8(X) X(0) X(1) X(2) X(3) X(4) X(5) X(6) X(7)
#define LIST16(X) LIST8(X) \
  X(8) X(9) X(10) X(11) X(12) X(13) X(14) X(15)

#define LIST64(X) \
  X(0) X(1) X(2) X(3) X(4) X(5) X(6) X(7) \
  X(8) X(9) X(10) X(11) X(12) X(13) X(14) X(15) \
  X(16) X(17) X(18) X(19) X(20) X(21) X(22) X(23) \
  X(24) X(25) X(26) X(27) X(28) X(29) X(30) X(31) \
  X(32) X(33) X(34) X(35) X(36) X(37) X(38) X(39) \
  X(40) X(41) X(42) X(43) X(44) X(45) X(46) X(47) \
  X(48) X(49) X(50) X(51) X(52) X(53) X(54) X(55) \
  X(56) X(57) X(58) X(59) X(60) X(61) X(62) X(63)

#define QUADS16(X) \
  X(0,0,1,2,3)     X(1,4,5,6,7)     X(2,8,9,10,11)   X(3,12,13,14,15) \
  X(4,16,17,18,19) X(5,20,21,22,23) X(6,24,25,26,27) X(7,28,29,30,31) \
  X(8,32,33,34,35) X(9,36,37,38,39) X(10,40,41,42,43) X(11,44,45,46,47) \
  X(12,48,49,50,51) X(13,52,53,54,55) X(14,56,57,58,59) X(15,60,61,62,63)

// pack two floats into one uint of f16x2 (a = low element), RTE
__device__ __forceinline__ unsigned pack_h2(float a, float b) {
  unsigned short ua = __builtin_bit_cast(unsigned short, (_Float16)a);
  unsigned short ub = __builtin_bit_cast(unsigned short, (_Float16)b);
  return ((unsigned)ub << 16) | ua;
}
__device__ __forceinline__ unsigned short f16bits(float a) {
  return __builtin_bit_cast(unsigned short, (_Float16)a);
}
__device__ __forceinline__ float f16val(unsigned short u) {
  return (float)__builtin_bit_cast(_Float16, u);
}

// acc += dot(f16x2 w, f16x2 h), fp32 accumulate (v_dot2_f32_f16).
// R11 A/B verdict: 2x v_fma_mix_f32 is SLOWER (5590 vs 4908) — dot2 is the
// right instruction; reverted.
__device__ __forceinline__ float dot2(unsigned w, unsigned h, float acc) {
#ifdef USE_DOT2
  return __builtin_amdgcn_fdot2(__builtin_bit_cast(h2, w),
                                __builtin_bit_cast(h2, h), acc, false);
#else
  h2 wv = __builtin_bit_cast(h2, w), hv = __builtin_bit_cast(h2, h);
  return __builtin_fmaf((float)wv[1], (float)hv[1],
                        __builtin_fmaf((float)wv[0], (float)hv[0], acc));
#endif
}

__device__ __forceinline__ float fast_sigmoid(float x) {
  return 1.0f / (1.0f + __expf(-x));
}
__device__ __forceinline__ float fast_tanh(float x) {
  return 2.0f / (1.0f + __expf(-2.0f * x)) - 1.0f;
}

// DPP quad_perm cross-lane moves within 4-lane groups (pure VALU, no LDS):
// xor1 = quad_perm[1,0,3,2] = 0xB1 ; xor2 = quad_perm[2,3,0,1] = 0x4E
__device__ __forceinline__ float dppx1m(float x) {
  return __builtin_bit_cast(float,
      __builtin_amdgcn_update_dpp(0, __builtin_bit_cast(int, x), 0xB1, 0xF, 0xF, true));
}
__device__ __forceinline__ float dppx2m(float x) {
  return __builtin_bit_cast(float,
      __builtin_amdgcn_update_dpp(0, __builtin_bit_cast(int, x), 0x4E, 0xF, 0xF, true));
}
// sum across the 4-lane group (all lanes end with the group total)
__device__ __forceinline__ float bfly4(float x) {
  x += dppx1m(x);
  x += dppx2m(x);
  return x;
}

// LDS-only barrier: drains LDS ops (the h dbuf handoff) but NOT vmcnt, so
// ring stores / prefetch loads stay in flight across steps.
__device__ __forceinline__ void lds_barrier() {
  asm volatile("s_waitcnt lgkmcnt(0)" ::: "memory");
  __builtin_amdgcn_s_barrier();
  asm volatile("" ::: "memory");
}

// ---------------------------------------------------------------------------
// gx precompute: gx[d][t][u][gate] = f16( b0 + W_ih0_row . x[d][t] )
// TRANSPOSED inner layout (unit-major, gate-minor).
// ---------------------------------------------------------------------------
__global__ __launch_bounds__(512)
void gx_kernel(const float* __restrict__ shared_in,  // [T, S]
               const float* __restrict__ perdev,     // [D, T, P]
               const float* __restrict__ Wih0,       // [D, 4H, S+P]
               const float* __restrict__ b0,         // [D, 4H]
               unsigned short* __restrict__ gx)      // [D, T, 128, 4] f16
{
  const int d = blockIdx.y;
  const int t0 = blockIdx.x * GXTB;
  const int g = threadIdx.x;          // gate row 0..511
  const int u = g & 127;              // hidden unit
  const int gate = g >> 7;            // 0..3 (i,f,g,o)

  __shared__ unsigned xs[GXTB * XPAIRS];  // x tile, packed f16x2

  const float* p = Wih0 + (size_t)(d * NG + g) * XD;
  uv16 w0, w1;
  uv4 w2;
#pragma unroll
  for (int j = 0; j < 16; ++j) w0[j] = pack_h2(p[2 * j], p[2 * j + 1]);
#pragma unroll
  for (int j = 0; j < 16; ++j) w1[j] = pack_h2(p[32 + 2 * j], p[33 + 2 * j]);
#pragma unroll
  for (int j = 0; j < 4; ++j) w2[j] = pack_h2(p[64 + 2 * j], p[65 + 2 * j]);
  const float b0g = b0[d * NG + g];

  for (int i = g; i < GXTB * XPAIRS; i += 512) {
    int r = i / XPAIRS, j = i - r * XPAIRS, t = t0 + r;
    float a, b;
    if (j < SD / 2) {
      a = shared_in[t * SD + 2 * j];
      b = shared_in[t * SD + 2 * j + 1];
    } else {
      int k = 2 * (j - SD / 2);
      a = perdev[((size_t)d * TT + t) * PD + k];
      b = perdev[((size_t)d * TT + t) * PD + k + 1];
    }
    xs[i] = pack_h2(a, b);
  }
  __syncthreads();

#define WJ(j) ((j) < 16 ? w0[(j)] : ((j) < 32 ? w1[(j)-16] : w2[(j)-32]))
  for (int tt = 0; tt < GXTB; ++tt) {
    const unsigned* xr = &xs[tt * XPAIRS];
    float a0 = b0g, a1 = 0.f, a2 = 0.f, a3 = 0.f;
#pragma unroll
    for (int j = 0; j < XPAIRS; j += 4) {
      a0 = dot2(WJ(j + 0), xr[j + 0], a0);
      a1 = dot2(WJ(j + 1), xr[j + 1], a1);
      a2 = dot2(WJ(j + 2), xr[j + 2], a2);
      a3 = dot2(WJ(j + 3), xr[j + 3], a3);
    }
    gx[((size_t)d * TT + t0 + tt) * NG + u * 4 + gate] = f16bits((a0 + a1) + (a2 + a3));
  }
#undef WJ
}

// ---------------------------------------------------------------------------
// Round-12 = R10 cross-CU layer pipeline (best verified: 4908 steady, builtin
// fdot2) + ONLY the two unconfounded R11 riders:
//  1. SAME-XCD pairing: producer = block d (d<32), consumer = block d+32 ->
//     both on XCD d%8 (round-robin dispatch) -> ring reads L2-local. R11
//     showed the signature (FETCH 219GB -> 84GB) but bundled the fma_mix
//     regression; this round isolates it.
//  2. s_sleep(1) poll granularity.
// dot2 REVERTED to v_dot2_f32_f16 (R11 A/B: fma_mix is slower).
// ---------------------------------------------------------------------------
__global__ __attribute__((amdgpu_flat_work_group_size(512, 512), amdgpu_waves_per_eu(2, 2)))
void lstm_split_kernel(const float* __restrict__ Whh0,        // [D, 4H, H]
                       const float* __restrict__ Wih1,        // [D, 4H, H]
                       const float* __restrict__ Whh1,        // [D, 4H, H]
                       const float* __restrict__ b1,          // [D, 4H]
                       const float* __restrict__ Wout,        // [D, H]
                       const float* __restrict__ bout,        // [D]
                       const unsigned short* __restrict__ gx, // [D, T, 128, 4] f16
                       float* __restrict__ out,               // [T, D]
                       unsigned short* __restrict__ h0buf,    // [D][RING][HH] f16
                       float* __restrict__ zbuf,              // [D][RING][NG] f32
                       int* __restrict__ prog,                // [D*16] producer progress
                       int* __restrict__ cprog)               // [D*16] consumer progress
{
  const int d = blockIdx.x & 31;           // device
  const bool producer = blockIdx.x < DD;   // blocks d and d+32 share XCD d%8
  const int tid = threadIdx.x;
  const int lam = tid & 3;
  const int u = tid >> 2;          // hidden unit 0..127
  const bool lp = (lam < 2);

  __shared__ __align__(16) unsigned hst_s[2][HH / 2]; // producer: h0 dbuf / consumer: h1 dbuf
  __shared__ float part2_s[16][HH];                   // consumer: wout*h1 ring (by t&15)
  __shared__ int flag_s;

  const float actS = (lam == 2) ? 2.f : 1.f;
  const float actA = (lam == 2) ? -1.f : 0.f;

  if (tid < HH / 2) { hst_s[0][tid] = 0u; hst_s[1][tid] = 0u; }

  if (producer) {
    // ---- weights: Whh0 wA..wD (16 each, K [lam*32,+32)); Wih1 K-lo wE..wH
    // (8 each, K [lam*16,+16)) ----
#define DWA(n) unsigned wA##n;
    LIST16(DWA)
#undef DWA
#define DWB(n) unsigned wB##n;
    LIST16(DWB)
#undef DWB
#define DWC(n) unsigned wC##n;
    LIST16(DWC)
#undef DWC
#define DWD(n) unsigned wD##n;
    LIST16(DWD)
#undef DWD
#define DWE(n) unsigned wE##n;
    LIST8(DWE)
#undef DWE
#define DWF(n) unsigned wF##n;
    LIST8(DWF)
#undef DWF
#define DWG(n) unsigned wG##n;
    LIST8(DWG)
#undef DWG
#define DWH(n) unsigned wH##n;
    LIST8(DWH)
#undef DWH
    {
      const float* pw = Whh0 + ((size_t)d * NG + u) * HH + lam * 32;
#define LWA(n) wA##n = pack_h2(pw[2 * (n)], pw[2 * (n) + 1]);
      LIST16(LWA)
#undef LWA
      pw += (size_t)128 * HH;
#define LWB(n) wB##n = pack_h2(pw[2 * (n)], pw[2 * (n) + 1]);
      LIST16(LWB)
#undef LWB
      pw += (size_t)128 * HH;
#define LWC(n) wC##n = pack_h2(pw[2 * (n)], pw[2 * (n) + 1]);
      LIST16(LWC)
#undef LWC
      pw += (size_t)128 * HH;
#define LWD(n) wD##n = pack_h2(pw[2 * (n)], pw[2 * (n) + 1]);
      LIST16(LWD)
#undef LWD
      const float* qw = Wih1 + ((size_t)d * NG + u) * HH + lam * 16;
#define LWE(n) wE##n = pack_h2(qw[2 * (n)], qw[2 * (n) + 1]);
      LIST8(LWE)
#undef LWE
      qw += (size_t)128 * HH;
#define LWF(n) wF##n = pack_h2(qw[2 * (n)], qw[2 * (n) + 1]);
      LIST8(LWF)
#undef LWF
      qw += (size_t)128 * HH;
#define LWG(n) wG##n = pack_h2(qw[2 * (n)], qw[2 * (n) + 1]);
      LIST8(LWG)
#undef LWG
      qw += (size_t)128 * HH;
#define LWH(n) wH##n = pack_h2(qw[2 * (n)], qw[2 * (n) + 1]);
      LIST8(LWH)
#undef LWH
    }

    const unsigned short* gp = gx + (size_t)d * TT * NG + tid;
    unsigned short gxc = gp[0], gxn = 0;
    unsigned short* h0base = h0buf + (size_t)d * RING * HH;
    float* zbase = zbuf + (size_t)d * RING * NG;
    float c0 = 0.f;
    int cons_seen = -1;

    __syncthreads();

    for (int k = 0; k <= TT; ++k) {
      const int rb = (k & 1) ^ 1;
      const int wb = k & 1;
      if (k + 1 < TT) gxn = gp[(size_t)(k + 1) * NG];

      const uint4* hp = (const uint4*)hst_s[rb];
      uint4 q0 = hp[lam * 4 + 0], q1 = hp[lam * 4 + 1],
            q2 = hp[lam * 4 + 2], q3 = hp[lam * 4 + 3];
      uint4 e0 = hp[lam * 2], e1 = hp[lam * 2 + 1];  // K-lo slice (broadcast)

      // ---- layer 0 for t=k ----
      if (k < TT) {
        float aA = 0.f, aB = 0.f, aC = 0.f, aD = 0.f;
#define A0S(j, HV) { aA = dot2(wA##j, HV, aA); aB = dot2(wB##j, HV, aB); \
                     aC = dot2(wC##j, HV, aC); aD = dot2(wD##j, HV, aD); }
        A0S(0, q0.x)  A0S(1, q0.y)  A0S(2, q0.z)  A0S(3, q0.w)
        A0S(4, q1.x)  A0S(5, q1.y)  A0S(6, q1.z)  A0S(7, q1.w)
        A0S(8, q2.x)  A0S(9, q2.y)  A0S(10, q2.z) A0S(11, q2.w)
        A0S(12, q3.x) A0S(13, q3.y) A0S(14, q3.z) A0S(15, q3.w)
#undef A0S
        aA = bfly4(aA); aB = bfly4(aB); aC = bfly4(aC); aD = bfly4(aD);
        float pre = (lam == 0) ? aA : (lam == 1) ? aB : (lam == 2) ? aC : aD;
        pre += f16val(gxc);
        float e = __expf(-actS * pre);
        float act = __builtin_fmaf(1.f / (1.f + e), actS, actA);
        float v1 = dppx1m(act);
        float lo = (lam & 1) ? v1 : act;
        float hi = (lam & 1) ? act : v1;
        float lo2 = dppx2m(lo);
        float hi2 = dppx2m(hi);
        float ig = lp ? lo : lo2;
        float fg = lp ? hi : hi2;
        float gg = lp ? lo2 : lo;
        float og = lp ? hi2 : hi;
        c0 = __builtin_fmaf(fg, c0, ig * gg);
        float h0n = og * fast_tanh(c0);
        if (lam == 0) {
          unsigned short hb = f16bits(h0n);
          ((unsigned short*)hst_s[wb])[u] = hb;
          h0base[(size_t)(k & RMASK) * HH + u] = hb;
        }
      }

      // ---- z_lo(k-1) = Wih1[:,0:64] . h0(k-1) ----
      if (k >= 1) {
        float aE = 0.f, aF = 0.f, aG = 0.f, aH = 0.f;
#define Z0S(j, HV) { aE = dot2(wE##j, HV, aE); aF = dot2(wF##j, HV, aF); \
                     aG = dot2(wG##j, HV, aG); aH = dot2(wH##j, HV, aH); }
        Z0S(0, e0.x) Z0S(1, e0.y) Z0S(2, e0.z) Z0S(3, e0.w)
        Z0S(4, e1.x) Z0S(5, e1.y) Z0S(6, e1.z) Z0S(7, e1.w)
#undef Z0S
        aE = bfly4(aE); aF = bfly4(aF); aG = bfly4(aG); aH = bfly4(aH);
        float zr = (lam == 0) ? aE : (lam == 1) ? aF : (lam == 2) ? aG : aH;
        zbase[(size_t)((k - 1) & RMASK) * NG + tid] = zr;
      }

      // ---- barrier: lgkm-only per step; FULL drain only at the publish ----
      if ((k & 7) == 7 || k == TT) {
        __syncthreads();   // vmcnt(0) drain of everyone's ring stores
        if (tid == 0) {
          __hip_atomic_store(&prog[d * 16], k, __ATOMIC_RELEASE, __HIP_MEMORY_SCOPE_AGENT);
          if (k < TT) {  // throttle: never more than 40 steps ahead (ring safety)
            int c = cons_seen;
            while (k - c > 40) {
              __builtin_amdgcn_s_sleep(1);
              c = __hip_atomic_load(&cprog[d * 16], __ATOMIC_ACQUIRE, __HIP_MEMORY_SCOPE_AGENT);
            }
            cons_seen = c;
          }
        }
        __syncthreads();
      } else {
        lds_barrier();
      }
      gxc = gxn;
    }
  } else {
    // ================= consumer =================
    // weights: Wih1 K-hi wE..wH (8 each, K [64+lam*16,+16)); Whh1 wI..wL
    // (16 each, K [lam*32,+32))
#define DWE(n) unsigned wE##n;
    LIST8(DWE)
#undef DWE
#define DWF(n) unsigned wF##n;
    LIST8(DWF)
#undef DWF
#define DWG(n) unsigned wG##n;
    LIST8(DWG)
#undef DWG
#define DWH(n) unsigned wH##n;
    LIST8(DWH)
#undef DWH
#define DWI(n) unsigned wI##n;
    LIST16(DWI)
#undef DWI
#define DWJ(n) unsigned wJ##n;
    LIST16(DWJ)
#undef DWJ
#define DWK(n) unsigned wK##n;
    LIST16(DWK)
#undef DWK
#define DWL(n) unsigned wL##n;
    LIST16(DWL)
#undef DWL
    {
      const float* qw = Wih1 + ((size_t)d * NG + u) * HH + 64 + lam * 16;
#define LWE(n) wE##n = pack_h2(qw[2 * (n)], qw[2 * (n) + 1]);
      LIST8(LWE)
#undef LWE
      qw += (size_t)128 * HH;
#define LWF(n) wF##n = pack_h2(qw[2 * (n)], qw[2 * (n) + 1]);
      LIST8(LWF)
#undef LWF
      qw += (size_t)128 * HH;
#define LWG(n) wG##n = pack_h2(qw[2 * (n)], qw[2 * (n) + 1]);
      LIST8(LWG)
#undef LWG
      qw += (size_t)128 * HH;
#define LWH(n) wH##n = pack_h2(qw[2 * (n)], qw[2 * (n) + 1]);
      LIST8(LWH)
#undef LWH
      const float* rw = Whh1 + ((size_t)d * NG + u) * HH + lam * 32;
#define LWI(n) wI##n = pack_h2(rw[2 * (n)], rw[2 * (n) + 1]);
      LIST16(LWI)
#undef LWI
      rw += (size_t)128 * HH;
#define LWJ(n) wJ##n = pack_h2(rw[2 * (n)], rw[2 * (n) + 1]);
      LIST16(LWJ)
#undef LWJ
      rw += (size_t)128 * HH;
#define LWK(n) wK##n = pack_h2(rw[2 * (n)], rw[2 * (n) + 1]);
      LIST16(LWK)
#undef LWK
      rw += (size_t)128 * HH;
#define LWL(n) wL##n = pack_h2(rw[2 * (n)], rw[2 * (n) + 1]);
      LIST16(LWL)
#undef LWL
    }
    const float b1sel = b1[(size_t)d * NG + u + lam * 128];
    const float woutu = Wout[(size_t)d * HH + u];
    const float boutd = bout[d];
    float c1 = 0.f;
    const unsigned short* h0base = h0buf + (size_t)d * RING * HH;
    const float* zbase = zbuf + (size_t)d * RING * NG;

    // initial poll: cover z(0..8) and h0(0..8)
    if (tid == 0) {
      int need = 9 > TT ? TT : 9;
      int p = -1;
      while (p < need) {
        __builtin_amdgcn_s_sleep(1);
        p = __hip_atomic_load(&prog[d * 16], __ATOMIC_ACQUIRE, __HIP_MEMORY_SCOPE_AGENT);
      }
      flag_s = p;
    }
    __syncthreads();

    // prologue loads: z(0), h0(0) K-hi slice
    float zc = zbase[tid];
    const uint4* h0r0 = (const uint4*)(h0base + 64);
    uint4 s0 = h0r0[lam * 2], s1 = h0r0[lam * 2 + 1];

    for (int t = 0; t <= TT; ++t) {
      if (t && (t & 7) == 0) {
        if (tid == 0) {
          int need = t + 9 > TT ? TT : t + 9;
          int p = flag_s;
          while (p < need) {
            __builtin_amdgcn_s_sleep(1);
            p = __hip_atomic_load(&prog[d * 16], __ATOMIC_ACQUIRE, __HIP_MEMORY_SCOPE_AGENT);
          }
          flag_s = p;
        }
        __syncthreads();
      }

      // ---- amortized output flush: every 8 steps all 8 waves in parallel,
      // wave w reduces t' = t-8+w (slots (t-8..t-1)&15, disjoint from this
      // step's write slot t&15).
      if (t >= 8 && (t & 7) == 0) {
        const int e = t - 8 + (tid >> 6);
        const int l = tid & 63;
        float pv = part2_s[e & 15][l] + part2_s[e & 15][l + 64];
#pragma unroll
        for (int off = 32; off > 0; off >>= 1) pv += __shfl_xor(pv, off, 64);
        if (l == 0) out[(size_t)e * DD + d] = pv + boutd;
      }

      // prefetch next-step z and h0 slice
      float zn = zc;
      uint4 n0 = s0, n1 = s1;
      if (t + 1 < TT) {
        zn = zbase[(size_t)((t + 1) & RMASK) * NG + tid];
        const uint4* hr = (const uint4*)(h0base + (size_t)((t + 1) & RMASK) * HH + 64);
        n0 = hr[lam * 2]; n1 = hr[lam * 2 + 1];
      }

      if (t < TT) {
        const int rb = (t & 1) ^ 1;
        const uint4* ip = (const uint4*)hst_s[rb];
        uint4 r0 = ip[lam * 4 + 0], r1 = ip[lam * 4 + 1],
              r2 = ip[lam * 4 + 2], r3 = ip[lam * 4 + 3];
        float aE = 0.f, aF = 0.f, aG = 0.f, aH = 0.f;
        float aI = 0.f, aJ = 0.f, aK = 0.f, aL = 0.f;
#define C1S(j, HV) { aE = dot2(wE##j, HV, aE); aF = dot2(wF##j, HV, aF); \
                     aG = dot2(wG##j, HV, aG); aH = dot2(wH##j, HV, aH); }
        C1S(0, s0.x) C1S(1, s0.y) C1S(2, s0.z) C1S(3, s0.w)
        C1S(4, s1.x) C1S(5, s1.y) C1S(6, s1.z) C1S(7, s1.w)
#undef C1S
#define C2S(j, HV) { aI = dot2(wI##j, HV, aI); aJ = dot2(wJ##j, HV, aJ); \
                     aK = dot2(wK##j, HV, aK); aL = dot2(wL##j, HV, aL); }
        C2S(0, r0.x)  C2S(1, r0.y)  C2S(2, r0.z)  C2S(3, r0.w)
        C2S(4, r1.x)  C2S(5, r1.y)  C2S(6, r1.z)  C2S(7, r1.w)
        C2S(8, r2.x)  C2S(9, r2.y)  C2S(10, r2.z) C2S(11, r2.w)
        C2S(12, r3.x) C2S(13, r3.y) C2S(14, r3.z) C2S(15, r3.w)
#undef C2S
        aE += aI; aF += aJ; aG += aK; aH += aL;
        aE = bfly4(aE); aF = bfly4(aF); aG = bfly4(aG); aH = bfly4(aH);
        float pre = (lam == 0) ? aE : (lam == 1) ? aF : (lam == 2) ? aG : aH;
        pre += zc + b1sel;
        float e = __expf(-actS * pre);
        float act = __builtin_fmaf(1.f / (1.f + e), actS, actA);
        float v1 = dppx1m(act);
        float lo = (lam & 1) ? v1 : act;
        float hi = (lam & 1) ? act : v1;
        float lo2 = dppx2m(lo);
        float hi2 = dppx2m(hi);
        float ig = lp ? lo : lo2;
        float fg = lp ? hi : hi2;
        float gg = lp ? lo2 : lo;
        float og = lp ? hi2 : hi;
        c1 = __builtin_fmaf(fg, c1, ig * gg);
        float h1n = og * fast_tanh(c1);
        if (lam == 0) {
          ((unsigned short*)hst_s[t & 1])[u] = f16bits(h1n);
          part2_s[t & 15][u] = woutu * h1n;
        }
      }

      lds_barrier();
      zc = zn; s0 = n0; s1 = n1;

      if ((t & 7) == 7) {
        if (tid == 0)
          __hip_atomic_store(&cprog[d * 16], t, __ATOMIC_RELEASE, __HIP_MEMORY_SCOPE_AGENT);
      }
    }
  }
}

// ---------------------------------------------------------------------------
// Mid-fallback (ws fits gx only): Round-3 single-block fused kernel.
// ---------------------------------------------------------------------------
__global__ __attribute__((amdgpu_flat_work_group_size(512, 512), amdgpu_waves_per_eu(2, 2)))
void lstm_fused_kernel(const float* __restrict__ Whh0, const float* __restrict__ Wih1,
                       const float* __restrict__ Whh1, const float* __restrict__ b1,
                       const float* __restrict__ Wout, const float* __restrict__ bout,
                       const unsigned short* __restrict__ gx, float* __restrict__ out)
{
  const int d = blockIdx.x;
  const int tid = threadIdx.x;
  const int lam = tid & 3;
  const int u = tid >> 2;
  const bool lp = (lam < 2);

  __shared__ __align__(16) unsigned h0_s[2][HH / 2];
  __shared__ __align__(16) unsigned h1_s[2][HH / 2];
  __shared__ float part2_s[2][HH];

#define DWA(n) unsigned wA##n;
  LIST16(DWA)
#undef DWA
#define DWB(n) unsigned wB##n;
  LIST16(DWB)
#undef DWB
#define DWC(n) unsigned wC##n;
  LIST16(DWC)
#undef DWC
#define DWD(n) unsigned wD##n;
  LIST16(DWD)
#undef DWD
#define DWE(n) unsigned wE##n;
  LIST16(DWE)
#undef DWE
#define DWF(n) unsigned wF##n;
  LIST16(DWF)
#undef DWF
#define DWG(n) unsigned wG##n;
  LIST16(DWG)
#undef DWG
#define DWH(n) unsigned wH##n;
  LIST16(DWH)
#undef DWH
#define DWI(n) unsigned wI##n;
  LIST16(DWI)
#undef DWI
#define DWJ(n) unsigned wJ##n;
  LIST16(DWJ)
#undef DWJ
#define DWK(n) unsigned wK##n;
  LIST16(DWK)
#undef DWK
#define DWL(n) unsigned wL##n;
  LIST16(DWL)
#undef DWL
  {
    const float* pw = Whh0 + ((size_t)d * NG + u) * HH + lam * 32;
#define LWA(n) wA##n = pack_h2(pw[2 * (n)], pw[2 * (n) + 1]);
    LIST16(LWA)
#undef LWA
    pw += (size_t)128 * HH;
#define LWB(n) wB##n = pack_h2(pw[2 * (n)], pw[2 * (n) + 1]);
    LIST16(LWB)
#undef LWB
    pw += (size_t)128 * HH;
#define LWC(n) wC##n = pack_h2(pw[2 * (n)], pw[2 * (n) + 1]);
    LIST16(LWC)
#undef LWC
    pw += (size_t)128 * HH;
#define LWD(n) wD##n = pack_h2(pw[2 * (n)], pw[2 * (n) + 1]);
    LIST16(LWD)
#undef LWD
    const float* qw = Wih1 + ((size_t)d * NG + u) * HH + lam * 32;
#define LWE(n) wE##n = pack_h2(qw[2 * (n)], qw[2 * (n) + 1]);
    LIST16(LWE)
#undef LWE
    qw += (size_t)128 * HH;
#define LWF(n) wF##n = pack_h2(qw[2 * (n)], qw[2 * (n) + 1]);
    LIST16(LWF)
#undef LWF
    qw += (size_t)128 * HH;
#define LWG(n) wG##n = pack_h2(qw[2 * (n)], qw[2 * (n) + 1]);
    LIST16(LWG)
#undef LWG
    qw += (size_t)128 * HH;
#define LWH(n) wH##n = pack_h2(qw[2 * (n)], qw[2 * (n) + 1]);
    LIST16(LWH)
#undef LWH
    const float* rw = Whh1 + ((size_t)d * NG + u) * HH + lam * 32;
#define LWI(n) wI##n = pack_h2(rw[2 * (n)], rw[2 * (n) + 1]);
    LIST16(LWI)
#undef LWI
    rw += (size_t)128 * HH;
#define LWJ(n) wJ##n = pack_h2(rw[2 * (n)], rw[2 * (n) + 1]);
    LIST16(LWJ)
#undef LWJ
    rw += (size_t)128 * HH;
#define LWK(n) wK##n = pack_h2(rw[2 * (n)], rw[2 * (n) + 1]);
    LIST16(LWK)
#undef LWK
    rw += (size_t)128 * HH;
#define LWL(n) wL##n = pack_h2(rw[2 * (n)], rw[2 * (n) + 1]);
    LIST16(LWL)
#undef LWL
  }

  const float actS = (lam == 2) ? 2.f : 1.f;
  const float actA = (lam == 2) ? -1.f : 0.f;
  const float b1sel = b1[(size_t)d * NG + u + lam * 128];
  const float woutu = Wout[(size_t)d * HH + u];
  const float boutd = bout[d];
  float c0 = 0.f, c1 = 0.f;

  if (tid < HH / 2) {
    h0_s[0][tid] = 0u; h0_s[1][tid] = 0u;
    h1_s[0][tid] = 0u; h1_s[1][tid] = 0u;
  }
  if (tid < HH) { part2_s[0][tid] = 0.f; part2_s[1][tid] = 0.f; }

  const unsigned short* gp = gx + (size_t)d * TT * NG + tid;
  unsigned short gxc = gp[0], gxn = 0;

  __syncthreads();

  for (int k = 0; k <= TT; ++k) {
    const int rb = (k & 1) ^ 1;
    const int wb = k & 1;
    if (k + 1 < TT) gxn = gp[(size_t)(k + 1) * NG];

    const uint4* hp = (const uint4*)h0_s[rb];
    const uint4* ip = (const uint4*)h1_s[rb];
    uint4 q0 = hp[lam * 4 + 0], q1 = hp[lam * 4 + 1],
          q2 = hp[lam * 4 + 2], q3 = hp[lam * 4 + 3];
    uint4 r0 = ip[lam * 4 + 0], r1 = ip[lam * 4 + 1],
          r2 = ip[lam * 4 + 2], r3 = ip[lam * 4 + 3];

    if (k >= 2 && tid < 64) {
      float pv = part2_s[rb][tid] + part2_s[rb][tid + 64];
#pragma unroll
      for (int off = 32; off > 0; off >>= 1) pv += __shfl_xor(pv, off, 64);
      if (tid == 0) out[(size_t)(k - 2) * DD + d] = pv + boutd;
    }

    if (k < TT) {
      float aA = 0.f, aB = 0.f, aC = 0.f, aD = 0.f;
#define A0S(j, HV) { aA = dot2(wA##j, HV, aA); aB = dot2(wB##j, HV, aB); \
                     aC = dot2(wC##j, HV, aC); aD = dot2(wD##j, HV, aD); }
      A0S(0, q0.x)  A0S(1, q0.y)  A0S(2, q0.z)  A0S(3, q0.w)
      A0S(4, q1.x)  A0S(5, q1.y)  A0S(6, q1.z)  A0S(7, q1.w)
      A0S(8, q2.x)  A0S(9, q2.y)  A0S(10, q2.z) A0S(11, q2.w)
      A0S(12, q3.x) A0S(13, q3.y) A0S(14, q3.z) A0S(15, q3.w)
#undef A0S
      aA = bfly4(aA); aB = bfly4(aB); aC = bfly4(aC); aD = bfly4(aD);
      float pre = (lam == 0) ? aA : (lam == 1) ? aB : (lam == 2) ? aC : aD;
      pre += f16val(gxc);
      float e = __expf(-actS * pre);
      float act = __builtin_fmaf(1.f / (1.f + e), actS, actA);
      float v1 = dppx1m(act);
      float lo = (lam & 1) ? v1 : act;
      float hi = (lam & 1) ? act : v1;
      float lo2 = dppx2m(lo);
      float hi2 = dppx2m(hi);
      float ig = lp ? lo : lo2;
      float fg = lp ? hi : hi2;
      float gg = lp ? lo2 : lo;
      float og = lp ? hi2 : hi;
      c0 = __builtin_fmaf(fg, c0, ig * gg);
      float h0n = og * fast_tanh(c0);
      if (lam == 0) ((unsigned short*)h0_s[wb])[u] = f16bits(h0n);
    }

    if (k >= 1) {
      float aE = 0.f, aF = 0.f, aG = 0.f, aH = 0.f;
#define E0S(j, HV) { aE = dot2(wE##j, HV, aE); aF = dot2(wF##j, HV, aF); \
                     aG = dot2(wG##j, HV, aG); aH = dot2(wH##j, HV, aH); }
      E0S(0, q0.x)  E0S(1, q0.y)  E0S(2, q0.z)  E0S(3, q0.w)
      E0S(4, q1.x)  E0S(5, q1.y)  E0S(6, q1.z)  E0S(7, q1.w)
      E0S(8, q2.x)  E0S(9, q2.y)  E0S(10, q2.z) E0S(11, q2.w)
      E0S(12, q3.x) E0S(13, q3.y) E0S(14, q3.z) E0S(15, q3.w)
#undef E0S
#define I0S(j, HV) { aE = dot2(wI##j, HV, aE); aF = dot2(wJ##j, HV, aF); \
                     aG = dot2(wK##j, HV, aG); aH = dot2(wL##j, HV, aH); }
      I0S(0, r0.x)  I0S(1, r0.y)  I0S(2, r0.z)  I0S(3, r0.w)
      I0S(4, r1.x)  I0S(5, r1.y)  I0S(6, r1.z)  I0S(7, r1.w)
      I0S(8, r2.x)  I0S(9, r2.y)  I0S(10, r2.z) I0S(11, r2.w)
      I0S(12, r3.x) I0S(13, r3.y) I0S(14, r3.z) I0S(15, r3.w)
#undef I0S
      aE = bfly4(aE); aF = bfly4(aF); aG = bfly4(aG); aH = bfly4(aH);
      float pre = (lam == 0) ? aE : (lam == 1) ? aF : (lam == 2) ? aG : aH;
      pre += b1sel;
      float e = __expf(-actS * pre);
      float act = __builtin_fmaf(1.f / (1.f + e), actS, actA);
      float v1 = dppx1m(act);
      float lo = (lam & 1) ? v1 : act;
      float hi = (lam & 1) ? act : v1;
      float lo2 = dppx2m(lo);
      float hi2 = dppx2m(hi);
      float ig = lp ? lo : lo2;
      float fg = lp ? hi : hi2;
      float gg = lp ? lo2 : lo;
      float og = lp ? hi2 : hi;
      c1 = __builtin_fmaf(fg, c1, ig * gg);
      float h1n = og * fast_tanh(c1);
      if (lam == 0) {
        ((unsigned short*)h1_s[wb])[u] = f16bits(h1n);
        part2_s[wb][u] = woutu * h1n;
      }
    }

    __syncthreads();
    gxc = gxn;
  }

  if (tid < 64) {
    float pv = part2_s[TT & 1][tid] + part2_s[TT & 1][tid + 64];
#pragma unroll
    for (int off = 32; off > 0; off >>= 1) pv += __shfl_xor(pv, off, 64);
    if (tid == 0) out[(size_t)(TT - 1) * DD + d] = pv + boutd;
  }
}

// ---------------------------------------------------------------------------
// Last fallback (no workspace): previous-session kernel, non-PRE path only.
// ---------------------------------------------------------------------------
template <bool PRE>
__global__ __attribute__((amdgpu_flat_work_group_size(512, 512), amdgpu_waves_per_eu(2, 2)))
void lstm_pd_kernel(const float* __restrict__ shared_in, const float* __restrict__ perdev,
                    const float* __restrict__ Wih0, const float* __restrict__ Whh0,
                    const float* __restrict__ b0, const float* __restrict__ Wih1,
                    const float* __restrict__ Whh1, const float* __restrict__ b1,
                    const float* __restrict__ Wout, const float* __restrict__ bout,
                    const unsigned short* __restrict__ gx, float* __restrict__ out)
{
  const int d = blockIdx.x;
  const int g = threadIdx.x;
  const int lane = g & 63;
  const int wave = g >> 6;

  __shared__ float act0_s[NG];
  __shared__ float act1_s[NG];
  __shared__ __align__(16) unsigned h0_s[HH / 2];
  __shared__ __align__(16) unsigned h1_s[HH / 2];
  __shared__ __align__(16) unsigned x_s[PRE ? 4 : (XPAIRS + 4)];
  __shared__ unsigned wih0_s[PRE ? 1 : (NG * WROW)];
  __shared__ float part_s[2];

#define DW(n) unsigned wa##n, wi##n, wh##n;
  LIST64(DW)
#undef DW
  {
    const float* pa = Whh0 + (size_t)(d * NG + g) * HH;
    const float* pi = Wih1 + (size_t)(d * NG + g) * HH;
    const float* ph = Whh1 + (size_t)(d * NG + g) * HH;
#define SW(n) wa##n = pack_h2(pa[2 * (n)], pa[2 * (n) + 1]); \
              wi##n = pack_h2(pi[2 * (n)], pi[2 * (n) + 1]); \
              wh##n = pack_h2(ph[2 * (n)], ph[2 * (n) + 1]);
    LIST64(SW)
#undef SW
  }

  float b0g = 0.f;
  if (!PRE) {
    const float* p = Wih0 + (size_t)(d * NG + g) * XD;
    for (int j = 0; j < XPAIRS; ++j) wih0_s[g * WROW + j] = pack_h2(p[2 * j], p[2 * j + 1]);
    b0g = b0[d * NG + g];
  }
  const float b1g = b1[d * NG + g];
  const bool is_tanh_gate = ((g >> 7) == 2);
  float c0 = 0.f, c1 = 0.f;
  const float woutu = (g < HH) ? Wout[d * HH + g] : 0.f;
  const float boutd = bout[d];

  if (g < HH / 2) { h0_s[g] = 0u; h1_s[g] = 0u; }

  float xa = 0.f, xb = 0.f;
  if (!PRE && g < XPAIRS) {
    if (g < SD / 2) {
      xa = shared_in[0 * SD + 2 * g];
      xb = shared_in[0 * SD + 2 * g + 1];
    } else {
      int k = 2 * (g - SD / 2);
      xa = perdev[((size_t)d * TT + 0) * PD + k];
      xb = perdev[((size_t)d * TT + 0) * PD + k + 1];
    }
  }

  __syncthreads();

  for (int t = 0; t < TT; ++t) {
    if (!PRE) {
      if (g < XPAIRS) x_s[g] = pack_h2(xa, xb);
      __syncthreads();
    }

    float a0 = b0g, a1 = 0.f, a2 = 0.f, a3 = 0.f;
    if (!PRE) {
      const unsigned* wrow = &wih0_s[g * WROW];
#pragma unroll
      for (int j = 0; j < XPAIRS; j += 4) {
        a0 = dot2(wrow[j + 0], x_s[j + 0], a0);
        a1 = dot2(wrow[j + 1], x_s[j + 1], a1);
        a2 = dot2(wrow[j + 2], x_s[j + 2], a2);
        a3 = dot2(wrow[j + 3], x_s[j + 3], a3);
      }
    }
    {
      const uint4* h4 = (const uint4*)h0_s;
#define DA(q, n0, n1, n2, n3) { \
      uint4 hv = h4[q]; \
      a0 = dot2(wa##n0, hv.x, a0); a1 = dot2(wa##n1, hv.y, a1); \
      a2 = dot2(wa##n2, hv.z, a2); a3 = dot2(wa##n3, hv.w, a3); }
      QUADS16(DA)
#undef DA
      float pre = (a0 + a1) + (a2 + a3);
      act0_s[g] = is_tanh_gate ? fast_tanh(pre) : fast_sigmoid(pre);
    }
    __syncthreads();

    if (g == 0 && t > 0) out[(size_t)(t - 1) * DD + d] = part_s[0] + part_s[1] + boutd;

    if (!PRE && g < XPAIRS && t + 1 < TT) {
      int tn = t + 1;
      if (g < SD / 2) {
        xa = shared_in[tn * SD + 2 * g];
        xb = shared_in[tn * SD + 2 * g + 1];
      } else {
        int k = 2 * (g - SD / 2);
        xa = perdev[((size_t)d * TT + tn) * PD + k];
        xb = perdev[((size_t)d * TT + tn) * PD + k + 1];
      }
    }

    if (g < HH) {
      float ig = act0_s[g], fg = act0_s[g + 128], gg = act0_s[g + 256], og = act0_s[g + 384];
      c0 = __builtin_fmaf(fg, c0, ig * gg);
      float h0n = og * fast_tanh(c0);
      ((unsigned short*)h0_s)[g] = f16bits(h0n);
    }
    __syncthreads();

    a0 = b1g; a1 = 0.f; a2 = 0.f; a3 = 0.f;
    {
      const uint4* h4 = (const uint4*)h0_s;
#define DI(q, n0, n1, n2, n3) { \
      uint4 hv = h4[q]; \
      a0 = dot2(wi##n0, hv.x, a0); a1 = dot2(wi##n1, hv.y, a1); \
      a2 = dot2(wi##n2, hv.z, a2); a3 = dot2(wi##n3, hv.w, a3); }
      QUADS16(DI)
#undef DI
      const uint4* g4 = (const uint4*)h1_s;
#define DH(q, n0, n1, n2, n3) { \
      uint4 hv = g4[q]; \
      a0 = dot2(wh##n0, hv.x, a0); a1 = dot2(wh##n1, hv.y, a1); \
      a2 = dot2(wh##n2, hv.z, a2); a3 = dot2(wh##n3, hv.w, a3); }
      QUADS16(DH)
#undef DH
      float pre = (a0 + a1) + (a2 + a3);
      act1_s[g] = is_tanh_gate ? fast_tanh(pre) : fast_sigmoid(pre);
    }
    __syncthreads();

    if (g < HH) {
      float ig = act1_s[g], fg = act1_s[g + 128], gg = act1_s[g + 256], og = act1_s[g + 384];
      c1 = __builtin_fmaf(fg, c1, ig * gg);
      float h1n = og * fast_tanh(c1);
      ((unsigned short*)h1_s)[g] = f16bits(h1n);
      float p = woutu * h1n;
#pragma unroll
      for (int off = 32; off > 0; off >>= 1) p += __shfl_down(p, off, 64);
      if (lane == 0) part_s[wave] = p;
    }
  }

  __syncthreads();
  if (g == 0) out[(size_t)(TT - 1) * DD + d] = part_s[0] + part_s[1] + boutd;
}

extern "C" void kernel_launch(void* const* d_in, const int* in_sizes, int n_in,
                              void* d_out, int out_size, void* d_ws, size_t ws_size,
                              hipStream_t stream) {
  const float* shared_in = (const float*)d_in[0];
  const float* perdev    = (const float*)d_in[1];
  const float* Wih0      = (const float*)d_in[2];
  const float* Whh0      = (const float*)d_in[3];
  const float* b0        = (const float*)d_in[4];
  const float* Wih1      = (const float*)d_in[5];
  const float* Whh1      = (const float*)d_in[6];
  const float* b1        = (const float*)d_in[7];
  const float* Wout      = (const float*)d_in[8];
  const float* bout      = (const float*)d_in[9];
  float* out = (float*)d_out;

  const size_t gx_bytes = (size_t)DD * TT * NG * sizeof(unsigned short);  // 128 MB
  // split-path workspace layout after gx:
  const size_t off_h0 = gx_bytes;                        // 512 KB used
  const size_t off_z  = gx_bytes + (1u << 20);           // 4 MB used
  const size_t off_fl = gx_bytes + (5u << 20);           // 16 KB used (prog+cprog)
  const size_t need_split = off_fl + 16384;

  if (ws_size >= need_split) {
    char* ws = (char*)d_ws;
    unsigned short* gxp = (unsigned short*)ws;
    unsigned short* h0buf = (unsigned short*)(ws + off_h0);
    float* zbuf = (float*)(ws + off_z);
    int* prog = (int*)(ws + off_fl);
    int* cprog = (int*)(ws + off_fl + 8192);
    hipMemsetAsync(ws + off_fl, 0xFF, 16384, stream);    // prog/cprog = -1
    gx_kernel<<<dim3(TT / GXTB, DD), dim3(512), 0, stream>>>(shared_in, perdev, Wih0, b0, gxp);
    lstm_split_kernel<<<dim3(2 * DD), dim3(512), 0, stream>>>(
        Whh0, Wih1, Whh1, b1, Wout, bout, gxp, out, h0buf, zbuf, prog, cprog);
  } else if (ws_size >= gx_bytes) {
    unsigned short* gxp = (unsigned short*)d_ws;
    gx_kernel<<<dim3(TT / GXTB, DD), dim3(512), 0, stream>>>(shared_in, perdev, Wih0, b0, gxp);
    lstm_fused_kernel<<<dim3(DD), dim3(512), 0, stream>>>(
        Whh0, Wih1, Whh1, b1, Wout, bout, gxp, out);
  } else {
    lstm_pd_kernel<false><<<dim3(DD), dim3(NG), 0, stream>>>(
        shared_in, perdev, Wih0, Whh0, b0, Wih1, Whh1, b1, Wout, bout, nullptr, out);
  }
}